// Round 4
// baseline (318.608 us; speedup 1.0000x reference)
//
#include <hip/hip_runtime.h>
#include <hip/hip_bf16.h>
#include <stdint.h>

#define B_ 8
#define K_ 2048
#define D_ 1024
#define NC 32
#define TC (K_ / NC)   // 64 timesteps per chunk

typedef float v4f __attribute__((ext_vector_type(4)));
typedef short v8s __attribute__((ext_vector_type(8)));

__device__ __forceinline__ unsigned short f2bf(float f) {
    __hip_bfloat16 h = __float2bfloat16(f);
    return *reinterpret_cast<unsigned short*>(&h);
}

__device__ __forceinline__ void async_ld16(const void* g, void* l) {
    __builtin_amdgcn_global_load_lds(
        (__attribute__((address_space(1))) void*)(void*)g,
        (__attribute__((address_space(3))) void*)l,
        16, 0, 0);
}

// ---------------- converter: W (fp32 [K][K]) -> bf16 [K][K] ----------------
__global__ void conv_w(const float* __restrict__ W, unsigned short* __restrict__ Wb) {
    int i = (blockIdx.x * 256 + threadIdx.x) * 4;
    float4 v = *(const float4*)(W + i);
    ushort4 o;
    o.x = f2bf(v.x); o.y = f2bf(v.y); o.z = f2bf(v.z); o.w = f2bf(v.w);
    *(ushort4*)(Wb + i) = o;
}

// ---------- converter+transpose: x fp32 [B][K][D] -> xT bf16 [B][D][K] ----------
__global__ void conv_x_t(const float* __restrict__ x, unsigned short* __restrict__ xT) {
    const int k0 = blockIdx.x * 64, d0 = blockIdx.y * 64, bb = blockIdx.z;
    __shared__ unsigned short tile[64][68];   // pad 68 to break bank alignment
    const int tid = threadIdx.x;
    const int tx = tid & 15, ty = tid >> 4;
    const float* xp = x + (size_t)bb * K_ * D_;
#pragma unroll
    for (int r = 0; r < 4; r++) {
        int row = ty + r * 16;
        float4 v = *(const float4*)(xp + (size_t)(k0 + row) * D_ + d0 + tx * 4);
        tile[row][tx * 4 + 0] = f2bf(v.x);
        tile[row][tx * 4 + 1] = f2bf(v.y);
        tile[row][tx * 4 + 2] = f2bf(v.z);
        tile[row][tx * 4 + 3] = f2bf(v.w);
    }
    __syncthreads();
    unsigned short* op = xT + (size_t)bb * D_ * K_;
#pragma unroll
    for (int r = 0; r < 4; r++) {
        int dcol = ty + r * 16;
        ushort4 u;
        u.x = tile[tx * 4 + 0][dcol];
        u.y = tile[tx * 4 + 1][dcol];
        u.z = tile[tx * 4 + 2][dcol];
        u.w = tile[tx * 4 + 3][dcol];
        *(ushort4*)(op + (size_t)(d0 + dcol) * K_ + k0 + tx * 4) = u;
    }
}

// ---------------- GEMM + bias + sigmoid: lam[b][t][d] ----------------
// Block tile 256(M=t) x 128(N=d), 4 waves, per-wave tile 128x64 (8x4 of 16x16).
// LDS fragment bytes per FLOP: 12 KB / 524288 = 1/43.7 (was 1/32 at 64x64 wave
// tile) -> raises the ds_read-BW ceiling from ~2720 to ~3710 FLOP/cyc/CU.
// Staging keeps the lane-linear global_load_lds pattern (R2: permuting source
// lanes cost 13%). BK=64 as two BK=32 sub-buffers, one barrier pair per 64 k.
__launch_bounds__(256)
__global__ void gemm_sig(const unsigned short* __restrict__ Wb,
                         const unsigned short* __restrict__ xT,
                         const float* __restrict__ bias,
                         float* __restrict__ lam) {
    const int tM = blockIdx.x, tN = blockIdx.y, bb = blockIdx.z;
    __shared__ unsigned short As[2][256 * 32];   // 32 KiB
    __shared__ unsigned short Bs[2][128 * 32];   // 16 KiB
    const int tid = threadIdx.x;
    const int w = tid >> 6;          // wave 0..3
    const int lane = tid & 63;
    const int wm = w >> 1, wn = w & 1;
    const int quad = lane >> 4;
    const int l16 = lane & 15;

    v4f acc[8][4];
#pragma unroll
    for (int i = 0; i < 8; i++)
#pragma unroll
        for (int j = 0; j < 4; j++) acc[i][j] = (v4f)0.f;

    const unsigned short* Ag = Wb + (size_t)(tM * 256) * K_;
    const unsigned short* Bg = xT + (size_t)bb * D_ * K_ + (size_t)(tN * 128) * K_;

    const int srow = lane >> 2;          // 0..15
    const int schunk = (lane & 3) * 8;   // lane-linear source (coalescing-friendly)

    for (int k0 = 0; k0 < K_; k0 += 64) {
#pragma unroll
        for (int h = 0; h < 2; h++) {
#pragma unroll
            for (int q = 0; q < 4; q++) {          // A: 256 rows in 16-row groups
                int rb = (q * 4 + w) * 16;
                async_ld16(Ag + (size_t)(rb + srow) * K_ + k0 + h * 32 + schunk, &As[h][rb * 32]);
            }
#pragma unroll
            for (int q = 0; q < 2; q++) {          // B: 128 rows
                int rb = (q * 4 + w) * 16;
                async_ld16(Bg + (size_t)(rb + srow) * K_ + k0 + h * 32 + schunk, &Bs[h][rb * 32]);
            }
        }
        __syncthreads();
#pragma unroll
        for (int h = 0; h < 2; h++) {
            v8s af[8], bfr[4];
#pragma unroll
            for (int i = 0; i < 8; i++)
                af[i] = *(const v8s*)(&As[h][(wm * 128 + i * 16 + l16) * 32 + quad * 8]);
#pragma unroll
            for (int j = 0; j < 4; j++)
                bfr[j] = *(const v8s*)(&Bs[h][(wn * 64 + j * 16 + l16) * 32 + quad * 8]);
#pragma unroll
            for (int i = 0; i < 8; i++)
#pragma unroll
                for (int j = 0; j < 4; j++)
                    acc[i][j] = __builtin_amdgcn_mfma_f32_16x16x32_bf16(af[i], bfr[j], acc[i][j], 0, 0, 0);
        }
        __syncthreads();
    }

    float* out = lam + (size_t)bb * K_ * D_;
#pragma unroll
    for (int i = 0; i < 8; i++) {
        int rowb = tM * 256 + wm * 128 + i * 16 + quad * 4;
#pragma unroll
        for (int r = 0; r < 4; r++) {
            float bt = bias[rowb + r];
#pragma unroll
            for (int j = 0; j < 4; j++) {
                int col = tN * 128 + wn * 64 + j * 16 + l16;
                float v = acc[i][j][r] + bt;
                out[(size_t)(rowb + r) * D_ + col] = 1.f / (1.f + __expf(-v));
            }
        }
    }
}

// -------- scan pass 1: per-(b,chunk,d2) affine composition (A,U), float2/lane --------
__global__ void scan_pass1(const float* __restrict__ lam, const float* __restrict__ x,
                           float* __restrict__ Ac, float* __restrict__ Uc) {
    int id = blockIdx.x * 256 + threadIdx.x;   // B*NC*D/2 = 131072
    int d2 = (id & 511) * 2;
    int c = (id >> 9) & (NC - 1);
    int bb = id >> 14;
    const float* lp = lam + ((size_t)bb * K_ + (size_t)c * TC) * D_ + d2;
    const float* xp = x   + ((size_t)bb * K_ + (size_t)c * TC) * D_ + d2;
    float2 A = make_float2(1.f, 1.f), U = make_float2(0.f, 0.f);
#pragma unroll 8
    for (int t = 0; t < TC; t++) {
        float2 l  = *(const float2*)(lp + (size_t)t * D_);
        float2 xv = *(const float2*)(xp + (size_t)t * D_);
        A.x *= l.x; A.y *= l.y;
        U.x = l.x * U.x + (1.f - l.x) * xv.x;
        U.y = l.y * U.y + (1.f - l.y) * xv.y;
    }
    size_t oi = ((size_t)bb * NC + c) * D_ + d2;
    *(float2*)(Ac + oi) = A;
    *(float2*)(Uc + oi) = U;
}

// -------- scan pass 2+3 merged: compose chunk-entry state from Ac/Uc (L2-hot,
// wave-uniform trip count), then replay chunk in-place over lam (=d_out) --------
__global__ void scan_pass23(const float* __restrict__ x,
                            const float* __restrict__ Ac, const float* __restrict__ Uc,
                            float* __restrict__ lamout) {
    int id = blockIdx.x * 256 + threadIdx.x;   // 131072
    int d2 = (id & 511) * 2;
    int c = (id >> 9) & (NC - 1);   // uniform within a block (256 threads span half a 512-group)
    int bb = id >> 14;
    float2 s = make_float2(0.f, 0.f);
    for (int cc = 0; cc < c; cc++) {
        size_t ai = ((size_t)bb * NC + cc) * D_ + d2;
        float2 a = *(const float2*)(Ac + ai);
        float2 u = *(const float2*)(Uc + ai);
        s.x = a.x * s.x + u.x;
        s.y = a.y * s.y + u.y;
    }
    float* lp = lamout + ((size_t)bb * K_ + (size_t)c * TC) * D_ + d2;
    const float* xp = x + ((size_t)bb * K_ + (size_t)c * TC) * D_ + d2;
#pragma unroll 8
    for (int t = 0; t < TC; t++) {
        float2 l  = *(const float2*)(lp + (size_t)t * D_);
        float2 xv = *(const float2*)(xp + (size_t)t * D_);
        s.x = l.x * s.x + (1.f - l.x) * xv.x;
        s.y = l.y * s.y + (1.f - l.y) * xv.y;
        *(float2*)(lp + (size_t)t * D_) = s;   // read-before-write, same thread
    }
}

extern "C" void kernel_launch(void* const* d_in, const int* in_sizes, int n_in,
                              void* d_out, int out_size, void* d_ws, size_t ws_size,
                              hipStream_t stream) {
    const float* x    = (const float*)d_in[0];
    const float* W    = (const float*)d_in[1];
    const float* bias = (const float*)d_in[2];
    float* out = (float*)d_out;
    char* ws = (char*)d_ws;

    unsigned short* xT = (unsigned short*)ws;                       // 32 MiB  [B][D][K] bf16
    unsigned short* Wb = (unsigned short*)(ws + 33554432);          // 8 MiB   [K][K] bf16
    // Ac/Uc (1 MiB each) overlay Wb's region — Wb is dead once gemm_sig completes.
    float* Ac  = (float*)(ws + 33554432);
    float* Uc  = (float*)(ws + 33554432 + 1048576);

    conv_w<<<dim3(K_ * K_ / 4 / 256), 256, 0, stream>>>(W, Wb);
    conv_x_t<<<dim3(K_ / 64, D_ / 64, B_), 256, 0, stream>>>(x, xT);
    // lam goes into d_out; pass23 overwrites it in place with the final scan output
    gemm_sig<<<dim3(K_ / 256, D_ / 128, B_), 256, 0, stream>>>(Wb, xT, bias, out);
    scan_pass1<<<dim3(B_ * NC * D_ / 2 / 256), 256, 0, stream>>>(out, x, Ac, Uc);
    scan_pass23<<<dim3(B_ * NC * D_ / 2 / 256), 256, 0, stream>>>(x, Ac, Uc, out);
}

// Round 5
// 279.088 us; speedup vs baseline: 1.1416x; 1.1416x over previous
//
#include <hip/hip_runtime.h>
#include <hip/hip_bf16.h>
#include <hip/hip_fp16.h>
#include <stdint.h>

#define B_ 8
#define K_ 2048
#define D_ 1024
#define NC 64
#define TC (K_ / NC)   // 32 timesteps per chunk

typedef float v4f __attribute__((ext_vector_type(4)));
typedef short v8s __attribute__((ext_vector_type(8)));

__device__ __forceinline__ unsigned short f2bf(float f) {
    __hip_bfloat16 h = __float2bfloat16(f);
    return *reinterpret_cast<unsigned short*>(&h);
}

__device__ __forceinline__ void async_ld16(const void* g, void* l) {
    __builtin_amdgcn_global_load_lds(
        (__attribute__((address_space(1))) void*)(void*)g,
        (__attribute__((address_space(3))) void*)l,
        16, 0, 0);
}

// ---------------- converter: W (fp32 [K][K]) -> bf16 [K][K] ----------------
__global__ void conv_w(const float* __restrict__ W, unsigned short* __restrict__ Wb) {
    int i = (blockIdx.x * 256 + threadIdx.x) * 4;
    float4 v = *(const float4*)(W + i);
    ushort4 o;
    o.x = f2bf(v.x); o.y = f2bf(v.y); o.z = f2bf(v.z); o.w = f2bf(v.w);
    *(ushort4*)(Wb + i) = o;
}

// ---------- converter+transpose: x fp32 [B][K][D] -> xT bf16 [B][D][K] ----------
__global__ void conv_x_t(const float* __restrict__ x, unsigned short* __restrict__ xT) {
    const int k0 = blockIdx.x * 64, d0 = blockIdx.y * 64, bb = blockIdx.z;
    __shared__ unsigned short tile[64][68];   // pad 68 to break bank alignment
    const int tid = threadIdx.x;
    const int tx = tid & 15, ty = tid >> 4;
    const float* xp = x + (size_t)bb * K_ * D_;
#pragma unroll
    for (int r = 0; r < 4; r++) {
        int row = ty + r * 16;
        float4 v = *(const float4*)(xp + (size_t)(k0 + row) * D_ + d0 + tx * 4);
        tile[row][tx * 4 + 0] = f2bf(v.x);
        tile[row][tx * 4 + 1] = f2bf(v.y);
        tile[row][tx * 4 + 2] = f2bf(v.z);
        tile[row][tx * 4 + 3] = f2bf(v.w);
    }
    __syncthreads();
    unsigned short* op = xT + (size_t)bb * D_ * K_;
#pragma unroll
    for (int r = 0; r < 4; r++) {
        int dcol = ty + r * 16;
        ushort4 u;
        u.x = tile[tx * 4 + 0][dcol];
        u.y = tile[tx * 4 + 1][dcol];
        u.z = tile[tx * 4 + 2][dcol];
        u.w = tile[tx * 4 + 3][dcol];
        *(ushort4*)(op + (size_t)(d0 + dcol) * K_ + k0 + tx * 4) = u;
    }
}

// ---------------- GEMM + bias + sigmoid ----------------
// R3 structure (proven best): 128x128 block tile, 4 waves @ 64x64, BK=64 as two
// BK=32 sub-buffers, lane-linear global_load_lds (R2: permuting lanes costs 13%).
// R4 falsified the LDS-BW model: 256x128 tile (VGPR 164 / LDS 48K, 2 blk/CU)
// regressed 43% — the structure is occupancy/barrier-latency bound; stay at 128^2.
// Template H: store lambda as fp16 to ws (halves lambda traffic here + both scans).
template<bool H>
__launch_bounds__(256)
__global__ void gemm_sig(const unsigned short* __restrict__ Wb,
                         const unsigned short* __restrict__ xT,
                         const float* __restrict__ bias,
                         void* __restrict__ lamv) {
    const int tM = blockIdx.x, tN = blockIdx.y, bb = blockIdx.z;
    __shared__ unsigned short As[2][128 * 32];
    __shared__ unsigned short Bs[2][128 * 32];
    const int tid = threadIdx.x;
    const int w = tid >> 6;
    const int lane = tid & 63;
    const int wm = w >> 1, wn = w & 1;
    const int quad = lane >> 4;
    const int l16 = lane & 15;

    v4f acc[4][4];
#pragma unroll
    for (int i = 0; i < 4; i++)
#pragma unroll
        for (int j = 0; j < 4; j++) acc[i][j] = (v4f)0.f;

    const unsigned short* Ag = Wb + (size_t)(tM * 128) * K_;
    const unsigned short* Bg = xT + (size_t)bb * D_ * K_ + (size_t)(tN * 128) * K_;

    const int srow = lane >> 2;          // 0..15
    const int schunk = (lane & 3) * 8;   // lane-linear source (coalescing-friendly)

    for (int k0 = 0; k0 < K_; k0 += 64) {
#pragma unroll
        for (int h = 0; h < 2; h++) {
#pragma unroll
            for (int q = 0; q < 2; q++) {
                int rb = (q * 4 + w) * 16;
                async_ld16(Ag + (size_t)(rb + srow) * K_ + k0 + h * 32 + schunk, &As[h][rb * 32]);
                async_ld16(Bg + (size_t)(rb + srow) * K_ + k0 + h * 32 + schunk, &Bs[h][rb * 32]);
            }
        }
        __syncthreads();
#pragma unroll
        for (int h = 0; h < 2; h++) {
            v8s af[4], bfr[4];
#pragma unroll
            for (int i = 0; i < 4; i++)
                af[i] = *(const v8s*)(&As[h][(wm * 64 + i * 16 + l16) * 32 + quad * 8]);
#pragma unroll
            for (int j = 0; j < 4; j++)
                bfr[j] = *(const v8s*)(&Bs[h][(wn * 64 + j * 16 + l16) * 32 + quad * 8]);
#pragma unroll
            for (int i = 0; i < 4; i++)
#pragma unroll
                for (int j = 0; j < 4; j++)
                    acc[i][j] = __builtin_amdgcn_mfma_f32_16x16x32_bf16(af[i], bfr[j], acc[i][j], 0, 0, 0);
        }
        __syncthreads();
    }

#pragma unroll
    for (int i = 0; i < 4; i++) {
        int rowb = tM * 128 + wm * 64 + i * 16 + quad * 4;
#pragma unroll
        for (int r = 0; r < 4; r++) {
            float bt = bias[rowb + r];
#pragma unroll
            for (int j = 0; j < 4; j++) {
                int col = tN * 128 + wn * 64 + j * 16 + l16;
                float v = acc[i][j][r] + bt;
                float sg = 1.f / (1.f + __expf(-v));
                size_t idx = ((size_t)bb * K_ + rowb + r) * D_ + col;
                if (H) ((__half*)lamv)[idx] = __float2half(sg);
                else   ((float*)lamv)[idx] = sg;
            }
        }
    }
}

__device__ __forceinline__ float2 load_lam(const void* lamv, size_t idx, bool H) {
    if (H) {
        __half2 h2 = *(const __half2*)((const __half*)lamv + idx);
        return __half22float2(h2);
    }
    return *(const float2*)((const float*)lamv + idx);
}

// -------- scan pass 1: per-(b,chunk,d2) affine composition (A,U), float2/lane --------
template<bool H>
__global__ void scan_pass1(const void* __restrict__ lamv, const float* __restrict__ x,
                           float* __restrict__ Ac, float* __restrict__ Uc) {
    int id = blockIdx.x * 256 + threadIdx.x;   // B*NC*D/2 = 262144
    int d2 = (id & 511) * 2;
    int c = (id >> 9) & (NC - 1);
    int bb = id >> 15;
    size_t base = ((size_t)bb * K_ + (size_t)c * TC) * D_ + d2;
    const float* xp = x + base;
    float2 A = make_float2(1.f, 1.f), U = make_float2(0.f, 0.f);
#pragma unroll 8
    for (int t = 0; t < TC; t++) {
        float2 l  = load_lam(lamv, base + (size_t)t * D_, H);
        float2 xv = *(const float2*)(xp + (size_t)t * D_);
        A.x *= l.x; A.y *= l.y;
        U.x = l.x * U.x + (1.f - l.x) * xv.x;
        U.y = l.y * U.y + (1.f - l.y) * xv.y;
    }
    size_t oi = ((size_t)bb * NC + c) * D_ + d2;
    *(float2*)(Ac + oi) = A;
    *(float2*)(Uc + oi) = U;
}

// -------- scan pass 2+3 merged: chunk-entry state from L2-hot Ac/Uc, then replay.
// NOTE: lamv and outp may alias (fp32 fallback path, in-place same-thread RBW) — no restrict.
template<bool H>
__global__ void scan_pass23(const float* __restrict__ x,
                            const float* __restrict__ Ac, const float* __restrict__ Uc,
                            const void* lamv, float* outp) {
    int id = blockIdx.x * 256 + threadIdx.x;   // 262144
    int d2 = (id & 511) * 2;
    int c = (id >> 9) & (NC - 1);
    int bb = id >> 15;
    float2 s = make_float2(0.f, 0.f);
    for (int cc = 0; cc < c; cc++) {
        size_t ai = ((size_t)bb * NC + cc) * D_ + d2;
        float2 a = *(const float2*)(Ac + ai);
        float2 u = *(const float2*)(Uc + ai);
        s.x = a.x * s.x + u.x;
        s.y = a.y * s.y + u.y;
    }
    size_t base = ((size_t)bb * K_ + (size_t)c * TC) * D_ + d2;
    const float* xp = x + base;
#pragma unroll 8
    for (int t = 0; t < TC; t++) {
        float2 l  = load_lam(lamv, base + (size_t)t * D_, H);
        float2 xv = *(const float2*)(xp + (size_t)t * D_);
        s.x = l.x * s.x + (1.f - l.x) * xv.x;
        s.y = l.y * s.y + (1.f - l.y) * xv.y;
        *(float2*)(outp + base + (size_t)t * D_) = s;
    }
}

extern "C" void kernel_launch(void* const* d_in, const int* in_sizes, int n_in,
                              void* d_out, int out_size, void* d_ws, size_t ws_size,
                              hipStream_t stream) {
    const float* x    = (const float*)d_in[0];
    const float* W    = (const float*)d_in[1];
    const float* bias = (const float*)d_in[2];
    float* out = (float*)d_out;
    char* ws = (char*)d_ws;

    const size_t MB = 1024 * 1024;
    unsigned short* xT = (unsigned short*)ws;                 // 32 MiB  [B][D][K] bf16
    unsigned short* Wb = (unsigned short*)(ws + 32 * MB);     // 8 MiB   [K][K] bf16
    // Ac/Uc (2 MiB each, NC=64) overlay Wb — Wb is dead once gemm_sig completes.
    float* Ac = (float*)(ws + 32 * MB);
    float* Uc = (float*)(ws + 34 * MB);
    __half* lamH = (__half*)(ws + 40 * MB);                   // 32 MiB (fp16 path only)

    const bool big = ws_size >= 72 * MB;

    conv_w<<<dim3(K_ * K_ / 4 / 256), 256, 0, stream>>>(W, Wb);
    conv_x_t<<<dim3(K_ / 64, D_ / 64, B_), 256, 0, stream>>>(x, xT);

    dim3 ggrid(K_ / 128, D_ / 128, B_);
    dim3 sgrid(B_ * NC * D_ / 2 / 256);
    if (big) {
        // lambda stored fp16 in ws: halves lambda traffic in gemm-write + both scans
        gemm_sig<true><<<ggrid, 256, 0, stream>>>(Wb, xT, bias, lamH);
        scan_pass1<true><<<sgrid, 256, 0, stream>>>(lamH, x, Ac, Uc);
        scan_pass23<true><<<sgrid, 256, 0, stream>>>(x, Ac, Uc, lamH, out);
    } else {
        // fallback: lambda fp32 in d_out, final scan overwrites it in place
        gemm_sig<false><<<ggrid, 256, 0, stream>>>(Wb, xT, bias, out);
        scan_pass1<false><<<sgrid, 256, 0, stream>>>(out, x, Ac, Uc);
        scan_pass23<false><<<sgrid, 256, 0, stream>>>(x, Ac, Uc, out, out);
    }
}